// Round 1
// baseline (224.919 us; speedup 1.0000x reference)
//
#include <hip/hip_runtime.h>
#include <hip/hip_bf16.h>
#include <stdint.h>

typedef unsigned short u16;
typedef unsigned int u32;
typedef __attribute__((ext_vector_type(8))) __bf16 bf16x8;
typedef __attribute__((ext_vector_type(8))) u16 u16x8;
typedef __attribute__((ext_vector_type(4))) float f32x4;
typedef __attribute__((ext_vector_type(4))) u32 u32x4;

__device__ __forceinline__ u16 f2bf(float f) {
  u32 u = __builtin_bit_cast(u32, f);
  u32 r = u + 0x7fffu + ((u >> 16) & 1u);   // round-to-nearest-even
  return (u16)(r >> 16);
}
__device__ __forceinline__ float bf2f(u16 h) {
  u32 u = ((u32)h) << 16;
  return __builtin_bit_cast(float, u);
}

__device__ __forceinline__ void gload_lds16(const void* g, void* l) {
  __builtin_amdgcn_global_load_lds(
      (const __attribute__((address_space(1))) void*)g,
      (__attribute__((address_space(3))) void*)l, 16, 0, 0);
}

// ---------------------------------------------------------------------------
// fp32 -> bf16 conversion (vectorized, grid-stride)
// ---------------------------------------------------------------------------
__global__ void f2bf_vec(const float* __restrict__ in, u16* __restrict__ out, int n4) {
  int i = blockIdx.x * blockDim.x + threadIdx.x;
  int stride = gridDim.x * blockDim.x;
  for (; i < n4; i += stride) {
    float4 v = ((const float4*)in)[i];
    ushort4 o;
    o.x = f2bf(v.x); o.y = f2bf(v.y); o.z = f2bf(v.z); o.w = f2bf(v.w);
    ((ushort4*)out)[i] = o;
  }
}

// ---------------------------------------------------------------------------
// C = A * B^T + bias.  A:[M,K] bf16, B:[N,K] bf16 (both row-major, K contig).
// 128x128 tile, BK=32, 4 waves (2x2), each wave 64x64 via 4x4 16x16x32 MFMA.
// global_load_lds width-16 staging (m97 structure).
// ---------------------------------------------------------------------------
template<int BF16_OUT>
__global__ __launch_bounds__(256) void gemm_bt(
    const u16* __restrict__ A, const u16* __restrict__ B,
    const float* __restrict__ bias, void* __restrict__ Cv,
    int M, int N, int K, int ldc) {
  __shared__ __align__(16) u16 As[128 * 32];
  __shared__ __align__(16) u16 Bs[128 * 32];
  const int tid = threadIdx.x;
  const int wid = tid >> 6, lane = tid & 63;
  const int l15 = lane & 15, l4 = lane >> 4;
  const int wr = wid >> 1, wc = wid & 1;
  const int bm = blockIdx.y * 128, bn = blockIdx.x * 128;

  f32x4 acc[4][4] = {};

  for (int k0 = 0; k0 < K; k0 += 32) {
#pragma unroll
    for (int i = 0; i < 2; ++i) {
      int c = i * 256 + wid * 64 + lane;              // chunk id (16B each)
      int row = c >> 2, kc = c & 3;
      gload_lds16(A + (size_t)(bm + row) * K + k0 + kc * 8,
                  (char*)As + (i * 256 + wid * 64) * 16);
      gload_lds16(B + (size_t)(bn + row) * K + k0 + kc * 8,
                  (char*)Bs + (i * 256 + wid * 64) * 16);
    }
    __syncthreads();   // compiler emits vmcnt(0) drain before barrier

    bf16x8 a[4], b[4];
#pragma unroll
    for (int mi = 0; mi < 4; ++mi)
      a[mi] = __builtin_bit_cast(bf16x8,
          *(const u32x4*)&As[(wr * 64 + mi * 16 + l15) * 32 + l4 * 8]);
#pragma unroll
    for (int ni = 0; ni < 4; ++ni)
      b[ni] = __builtin_bit_cast(bf16x8,
          *(const u32x4*)&Bs[(wc * 64 + ni * 16 + l15) * 32 + l4 * 8]);
#pragma unroll
    for (int mi = 0; mi < 4; ++mi)
#pragma unroll
      for (int ni = 0; ni < 4; ++ni)
        acc[mi][ni] = __builtin_amdgcn_mfma_f32_16x16x32_bf16(
            a[mi], b[ni], acc[mi][ni], 0, 0, 0);
    __syncthreads();
  }

  // epilogue: C[row][col], row = (l4*4+r), col = l15 within each 16x16 tile
#pragma unroll
  for (int ni = 0; ni < 4; ++ni) {
    int col = bn + wc * 64 + ni * 16 + l15;
    float bv = bias[col];
#pragma unroll
    for (int mi = 0; mi < 4; ++mi) {
      int row = bm + wr * 64 + mi * 16 + l4 * 4;
#pragma unroll
      for (int r = 0; r < 4; ++r) {
        float v = acc[mi][ni][r] + bv;
        if (BF16_OUT)
          ((u16*)Cv)[(size_t)(row + r) * ldc + col] = f2bf(v);
        else
          ((float*)Cv)[(size_t)(row + r) * ldc + col] = v;
      }
    }
  }
}

// ---------------------------------------------------------------------------
// Causal flash attention. qkv:[B*S, 3072] bf16 (Q|K|V concat), O:[B*S,1024] bf16.
// Block = 4 waves; each wave owns 16 q-rows of a 64-row q-tile. KV tiles of 64.
// ---------------------------------------------------------------------------
#define S_LEN 2048
#define E3 3072

__global__ __launch_bounds__(256) void attn_kernel(
    const u16* __restrict__ qkv, u16* __restrict__ O) {
  __shared__ __align__(16) u16 Ks[64 * 64];       // [kv][d], chunk-XOR swizzled
  __shared__ __align__(16) u16 Vt[64 * 64];       // [d][kv], XOR swizzled
  __shared__ __align__(16) u16 Ps[4][16 * 72];    // per-wave P, padded rows
  const int tid = threadIdx.x;
  const int wid = tid >> 6, lane = tid & 63;
  const int l15 = lane & 15, l4 = lane >> 4;
  const int qt = blockIdx.x;
  const int bh = blockIdx.y;
  const int b = bh >> 4, h = bh & 15;
  const int qb = qt * 64;
  const u16* base = qkv + (size_t)b * S_LEN * E3;
  const int qcol = h * 64, kcol = 1024 + h * 64, vcol = 2048 + h * 64;

  // Q fragments (A-operand layout: row = l15, k = l4*8+j), pre-scaled by 1/8
  bf16x8 qf[2];
  {
    int qrow = qb + wid * 16 + l15;
#pragma unroll
    for (int kf = 0; kf < 2; ++kf) {
      u16x8 raw = *(const u16x8*)&base[(size_t)qrow * E3 + qcol + kf * 32 + l4 * 8];
      u16x8 sc;
#pragma unroll
      for (int j = 0; j < 8; ++j) sc[j] = f2bf(bf2f(raw[j]) * 0.125f);
      qf[kf] = __builtin_bit_cast(bf16x8, sc);
    }
  }

  float m_[4], sum_[4];
  f32x4 o_[4] = {};
#pragma unroll
  for (int r = 0; r < 4; ++r) { m_[r] = -__builtin_inff(); sum_[r] = 0.f; }

  const int nkt = qt + 1;
  for (int kt = 0; kt < nkt; ++kt) {
    const int kvb = kt * 64;
    // ---- stage K (chunk-swizzled) and V^T (scalar transpose, swizzled) ----
#pragma unroll
    for (int i = 0; i < 2; ++i) {
      int c = i * 256 + tid;
      int kv = c >> 3, dch = c & 7;
      u32x4 kval = *(const u32x4*)&base[(size_t)(kvb + kv) * E3 + kcol + dch * 8];
      *(u32x4*)((char*)Ks + kv * 128 + ((dch ^ (kv & 7)) << 4)) = kval;
      u16x8 vval = *(const u16x8*)&base[(size_t)(kvb + kv) * E3 + vcol + dch * 8];
#pragma unroll
      for (int j = 0; j < 8; ++j) {
        int d = dch * 8 + j;
        *(u16*)((char*)Vt + d * 128 + ((kv * 2) ^ ((j ^ dch) << 4))) = vval[j];
      }
    }
    __syncthreads();

    // ---- S = (Q/8) K^T : 4 col-tiles x 2 k-steps ----
    f32x4 s[4] = {};
#pragma unroll
    for (int kf = 0; kf < 2; ++kf)
#pragma unroll
      for (int nt = 0; nt < 4; ++nt) {
        int krow = nt * 16 + l15;
        int slot = (kf * 4 + l4) ^ (krow & 7);
        bf16x8 kf8 = __builtin_bit_cast(bf16x8,
            *(const u32x4*)((const char*)Ks + krow * 128 + (slot << 4)));
        s[nt] = __builtin_amdgcn_mfma_f32_16x16x32_bf16(qf[kf], kf8, s[nt], 0, 0, 0);
      }

    // ---- causal mask (only the diagonal tile needs it) ----
    if (kt == qt) {
#pragma unroll
      for (int nt = 0; nt < 4; ++nt) {
        int col = kvb + nt * 16 + l15;
        int rowg = qb + wid * 16 + l4 * 4;
#pragma unroll
        for (int r = 0; r < 4; ++r)
          if (col > rowg + r) s[nt][r] = -__builtin_inff();
      }
    }

    // ---- online softmax (rows live in 16-lane groups; shfl_xor reduce) ----
    float pm[4], es[4], rs[4];
#pragma unroll
    for (int r = 0; r < 4; ++r)
      pm[r] = fmaxf(fmaxf(s[0][r], s[1][r]), fmaxf(s[2][r], s[3][r]));
#pragma unroll
    for (int r = 0; r < 4; ++r) {
#pragma unroll
      for (int off = 1; off < 16; off <<= 1)
        pm[r] = fmaxf(pm[r], __shfl_xor(pm[r], off));
      float nm = fmaxf(m_[r], pm[r]);
      es[r] = __expf(m_[r] - nm);
      m_[r] = nm;
      rs[r] = 0.f;
    }
#pragma unroll
    for (int nt = 0; nt < 4; ++nt)
#pragma unroll
      for (int r = 0; r < 4; ++r) {
        float p = __expf(s[nt][r] - m_[r]);
        s[nt][r] = p;
        rs[r] += p;
      }
#pragma unroll
    for (int r = 0; r < 4; ++r) {
#pragma unroll
      for (int off = 1; off < 16; off <<= 1)
        rs[r] += __shfl_xor(rs[r], off);
      sum_[r] = sum_[r] * es[r] + rs[r];
    }
#pragma unroll
    for (int dt = 0; dt < 4; ++dt)
#pragma unroll
      for (int r = 0; r < 4; ++r) o_[dt][r] *= es[r];

    // ---- P -> LDS (C-layout write), re-read in A-layout for PV ----
    u16* myP = &Ps[wid][0];
#pragma unroll
    for (int nt = 0; nt < 4; ++nt)
#pragma unroll
      for (int r = 0; r < 4; ++r)
        myP[(l4 * 4 + r) * 72 + nt * 16 + l15] = f2bf(s[nt][r]);
    __syncthreads();

    // ---- O += P V ----
#pragma unroll
    for (int kf = 0; kf < 2; ++kf) {
      bf16x8 pa = __builtin_bit_cast(bf16x8,
          *(const u32x4*)&myP[l15 * 72 + kf * 32 + l4 * 8]);
#pragma unroll
      for (int dt = 0; dt < 4; ++dt) {
        int d = dt * 16 + l15;
        int slot = (kf * 4 + l4) ^ (d & 7) ^ ((d >> 3) & 7);
        bf16x8 vf = __builtin_bit_cast(bf16x8,
            *(const u32x4*)((const char*)Vt + d * 128 + (slot << 4)));
        o_[dt] = __builtin_amdgcn_mfma_f32_16x16x32_bf16(pa, vf, o_[dt], 0, 0, 0);
      }
    }
    __syncthreads();  // protect Ks/Vt before next tile's staging
  }

  // ---- epilogue: normalize, store bf16 at [b*S+tok][h*64+d] ----
#pragma unroll
  for (int dt = 0; dt < 4; ++dt)
#pragma unroll
    for (int r = 0; r < 4; ++r) {
      float val = o_[dt][r] / sum_[r];
      int tok = qb + wid * 16 + l4 * 4 + r;
      O[(size_t)(b * S_LEN + tok) * 1024 + h * 64 + dt * 16 + l15] = f2bf(val);
    }
}

// ---------------------------------------------------------------------------
extern "C" void kernel_launch(void* const* d_in, const int* in_sizes, int n_in,
                              void* d_out, int out_size, void* d_ws, size_t ws_size,
                              hipStream_t stream) {
  const float* x    = (const float*)d_in[0];
  const float* Wqkv = (const float*)d_in[1];
  const float* bqkv = (const float*)d_in[2];
  const float* Wout = (const float*)d_in[3];
  const float* bout = (const float*)d_in[4];
  float* out = (float*)d_out;

  // workspace layout (u16 elems): 48 MiB total
  u16* xb    = (u16*)d_ws;            // 4,194,304
  u16* wqkvb = xb + 4194304;          // 3,145,728
  u16* woutb = wqkvb + 3145728;       // 1,048,576
  u16* qkvb  = woutb + 1048576;       // 12,582,912
  u16* ob    = qkvb + 12582912;       // 4,194,304

  f2bf_vec<<<1024, 256, 0, stream>>>(x,    xb,    4194304 / 4);
  f2bf_vec<<<1024, 256, 0, stream>>>(Wqkv, wqkvb, 3145728 / 4);
  f2bf_vec<<<512,  256, 0, stream>>>(Wout, woutb, 1048576 / 4);

  gemm_bt<1><<<dim3(24, 32), 256, 0, stream>>>(xb, wqkvb, bqkv, qkvb,
                                               4096, 3072, 1024, 3072);
  attn_kernel<<<dim3(32, 32), 256, 0, stream>>>(qkvb, ob);
  gemm_bt<0><<<dim3(8, 32), 256, 0, stream>>>(ob, woutb, bout, out,
                                              4096, 1024, 1024, 1024);
}

// Round 2
// 161.882 us; speedup vs baseline: 1.3894x; 1.3894x over previous
//
#include <hip/hip_runtime.h>
#include <hip/hip_bf16.h>
#include <stdint.h>

typedef unsigned short u16;
typedef unsigned int u32;
typedef __attribute__((ext_vector_type(8))) __bf16 bf16x8;
typedef __attribute__((ext_vector_type(8))) u16 u16x8;
typedef __attribute__((ext_vector_type(4))) u16 u16x4;
typedef __attribute__((ext_vector_type(4))) float f32x4;
typedef __attribute__((ext_vector_type(4))) u32 u32x4;

#define S_LEN 2048

__device__ __forceinline__ u16 f2bf(float f) {
  u32 u = __builtin_bit_cast(u32, f);
  u32 r = u + 0x7fffu + ((u >> 16) & 1u);   // round-to-nearest-even
  return (u16)(r >> 16);
}
__device__ __forceinline__ float bf2f(u16 h) {
  u32 u = ((u32)h) << 16;
  return __builtin_bit_cast(float, u);
}

__device__ __forceinline__ void gload_lds16(const void* g, void* l) {
  __builtin_amdgcn_global_load_lds(
      (const __attribute__((address_space(1))) void*)g,
      (__attribute__((address_space(3))) void*)l, 16, 0, 0);
}

// ---------------------------------------------------------------------------
// fp32 -> bf16 conversion (vectorized, grid-stride)
// ---------------------------------------------------------------------------
__global__ void f2bf_vec(const float* __restrict__ in, u16* __restrict__ out, int n4) {
  int i = blockIdx.x * blockDim.x + threadIdx.x;
  int stride = gridDim.x * blockDim.x;
  for (; i < n4; i += stride) {
    float4 v = ((const float4*)in)[i];
    ushort4 o;
    o.x = f2bf(v.x); o.y = f2bf(v.y); o.z = f2bf(v.z); o.w = f2bf(v.w);
    ((ushort4*)out)[i] = o;
  }
}

// ---------------------------------------------------------------------------
// C = A * B^T + bias.  A:[M,K] bf16, B:[N,K] bf16 (row-major, K contig).
// 128x128 tile, BK=32, 4 waves (2x2). MODE 0: fp32 C0 (ldc).
// MODE 2: QKV split — cols<2048 -> bf16 C0 (ld 2048); cols>=2048 (V) ->
//         transposed bf16 C1 as vt[b*16+h][d][s] (packed 4-row stores).
// ---------------------------------------------------------------------------
template<int MODE>
__global__ __launch_bounds__(256) void gemm_bt(
    const u16* __restrict__ A, const u16* __restrict__ B,
    const float* __restrict__ bias, void* __restrict__ C0,
    u16* __restrict__ C1, int M, int N, int K, int ldc) {
  __shared__ __align__(16) u16 As[128 * 32];
  __shared__ __align__(16) u16 Bs[128 * 32];
  const int tid = threadIdx.x;
  const int wid = tid >> 6, lane = tid & 63;
  const int l15 = lane & 15, l4 = lane >> 4;
  const int wr = wid >> 1, wc = wid & 1;
  const int bm = blockIdx.y * 128, bn = blockIdx.x * 128;

  f32x4 acc[4][4] = {};

  for (int k0 = 0; k0 < K; k0 += 32) {
#pragma unroll
    for (int i = 0; i < 2; ++i) {
      int c = i * 256 + wid * 64 + lane;              // chunk id (16B each)
      int row = c >> 2, kc = c & 3;
      gload_lds16(A + (size_t)(bm + row) * K + k0 + kc * 8,
                  (char*)As + (i * 256 + wid * 64) * 16);
      gload_lds16(B + (size_t)(bn + row) * K + k0 + kc * 8,
                  (char*)Bs + (i * 256 + wid * 64) * 16);
    }
    __syncthreads();

    bf16x8 a[4], b[4];
#pragma unroll
    for (int mi = 0; mi < 4; ++mi)
      a[mi] = __builtin_bit_cast(bf16x8,
          *(const u32x4*)&As[(wr * 64 + mi * 16 + l15) * 32 + l4 * 8]);
#pragma unroll
    for (int ni = 0; ni < 4; ++ni)
      b[ni] = __builtin_bit_cast(bf16x8,
          *(const u32x4*)&Bs[(wc * 64 + ni * 16 + l15) * 32 + l4 * 8]);
#pragma unroll
    for (int mi = 0; mi < 4; ++mi)
#pragma unroll
      for (int ni = 0; ni < 4; ++ni)
        acc[mi][ni] = __builtin_amdgcn_mfma_f32_16x16x32_bf16(
            a[mi], b[ni], acc[mi][ni], 0, 0, 0);
    __syncthreads();
  }

#pragma unroll
  for (int ni = 0; ni < 4; ++ni) {
    int col = bn + wc * 64 + ni * 16 + l15;
    float bv = bias[col];
#pragma unroll
    for (int mi = 0; mi < 4; ++mi) {
      int row = bm + wr * 64 + mi * 16 + l4 * 4;
      if (MODE == 0) {
#pragma unroll
        for (int r = 0; r < 4; ++r)
          ((float*)C0)[(size_t)(row + r) * ldc + col] = acc[mi][ni][r] + bv;
      } else {
        if (col < 2048) {
#pragma unroll
          for (int r = 0; r < 4; ++r)
            ((u16*)C0)[(size_t)(row + r) * 2048 + col] = f2bf(acc[mi][ni][r] + bv);
        } else {
          u16x4 vv;
#pragma unroll
          for (int r = 0; r < 4; ++r) vv[r] = f2bf(acc[mi][ni][r] + bv);
          int hh = (col - 2048) >> 6, d = (col - 2048) & 63;
          int bb = row >> 11, s = row & 2047;
          *(u16x4*)&C1[(((size_t)(bb * 16 + hh) * 64 + d) << 11) + s] = vv;
        }
      }
    }
  }
}

// ---------------------------------------------------------------------------
// Causal flash attention, causally balanced: block p handles q-tiles p and
// 31-p for one (b,h); both consume the same staged K/V tiles.
// qk:[4096][2048] bf16 (Q|K), vt:[32][64][2048] bf16 (V^T), O:[4096][1024].
// K and V^T staged via global_load_lds with pre-swizzled global sources
// (linear LDS dst), XOR-deswizzled on ds_read_b128.
// ---------------------------------------------------------------------------
__global__ __launch_bounds__(256, 2) void attn2(
    const u16* __restrict__ qk, const u16* __restrict__ vt, u16* __restrict__ O) {
  __shared__ __align__(16) u16 Ks[64 * 64];
  __shared__ __align__(16) u16 Vs[64 * 64];
  __shared__ __align__(16) u16 Ps[8][16 * 72];
  const int tid = threadIdx.x;
  const int wid = tid >> 6, lane = tid & 63;
  const int l15 = lane & 15, l4 = lane >> 4;
  const int p = blockIdx.x, bh = blockIdx.y;
  const int b = bh >> 4, h = bh & 15;
  const int qtA = p, qtB = 31 - p;
  const u16* qkb = qk + (((size_t)b * S_LEN) << 11);
  const u16* vtb = vt + ((size_t)bh << 17);           // 64*2048 per (b,h)
  const int qcol = h * 64, kcol = 1024 + h * 64;

  // staging chunk descriptors: chunk c -> row r = c>>3, swizzled col
  const int c0 = tid, c1 = 256 + tid;
  const int r0 = c0 >> 3, sw0 = ((c0 & 7) ^ (r0 & 7)) << 3;
  const int r1 = c1 >> 3, sw1 = ((c1 & 7) ^ (r1 & 7)) << 3;
  char* KsD0 = (char*)Ks + c0 * 16; char* KsD1 = (char*)Ks + c1 * 16;
  char* VsD0 = (char*)Vs + c0 * 16; char* VsD1 = (char*)Vs + c1 * 16;

  // Q fragments (A-layout: row=l15, k=l4*8+j), pre-scaled by 1/sqrt(64)
  bf16x8 qfA[2], qfB[2];
  {
    int rA = qtA * 64 + wid * 16 + l15;
    int rB = qtB * 64 + wid * 16 + l15;
#pragma unroll
    for (int kf = 0; kf < 2; ++kf) {
      u16x8 a = *(const u16x8*)&qkb[((size_t)rA << 11) + qcol + kf * 32 + l4 * 8];
      u16x8 bq = *(const u16x8*)&qkb[((size_t)rB << 11) + qcol + kf * 32 + l4 * 8];
      u16x8 sa, sb;
#pragma unroll
      for (int j = 0; j < 8; ++j) {
        sa[j] = f2bf(bf2f(a[j]) * 0.125f);
        sb[j] = f2bf(bf2f(bq[j]) * 0.125f);
      }
      qfA[kf] = __builtin_bit_cast(bf16x8, sa);
      qfB[kf] = __builtin_bit_cast(bf16x8, sb);
    }
  }

  float mA[4], lA[4], mB[4], lB[4];
  f32x4 oA[4] = {}, oB[4] = {};
#pragma unroll
  for (int r = 0; r < 4; ++r) {
    mA[r] = -__builtin_inff(); lA[r] = 0.f;
    mB[r] = -__builtin_inff(); lB[r] = 0.f;
  }

  // softmax + P write (Ps is wave-private: no barrier needed around it)
  auto smx = [&](f32x4* s, float* m_, float* l_, f32x4* o_, u16* myP) {
    float pm[4], es[4], rs[4];
#pragma unroll
    for (int r = 0; r < 4; ++r)
      pm[r] = fmaxf(fmaxf(s[0][r], s[1][r]), fmaxf(s[2][r], s[3][r]));
#pragma unroll
    for (int r = 0; r < 4; ++r) {
#pragma unroll
      for (int off = 1; off < 16; off <<= 1)
        pm[r] = fmaxf(pm[r], __shfl_xor(pm[r], off));
      float nm = fmaxf(m_[r], pm[r]);
      es[r] = __expf(m_[r] - nm);
      m_[r] = nm;
      rs[r] = 0.f;
    }
#pragma unroll
    for (int nt = 0; nt < 4; ++nt)
#pragma unroll
      for (int r = 0; r < 4; ++r) {
        float pv = __expf(s[nt][r] - m_[r]);
        s[nt][r] = pv;
        rs[r] += pv;
      }
#pragma unroll
    for (int r = 0; r < 4; ++r) {
#pragma unroll
      for (int off = 1; off < 16; off <<= 1)
        rs[r] += __shfl_xor(rs[r], off);
      l_[r] = l_[r] * es[r] + rs[r];
    }
#pragma unroll
    for (int dt = 0; dt < 4; ++dt)
#pragma unroll
      for (int r = 0; r < 4; ++r) o_[dt][r] *= es[r];
#pragma unroll
    for (int nt = 0; nt < 4; ++nt)
#pragma unroll
      for (int r = 0; r < 4; ++r)
        myP[(l4 * 4 + r) * 72 + nt * 16 + l15] = f2bf(s[nt][r]);
  };

  for (int kt = 0; kt <= qtB; ++kt) {
    const int kvb = kt << 6;
    // ---- stage K tile [kv][d] and V^T tile [d][kv] (pre-swizzled src) ----
    gload_lds16(qkb + (((size_t)(kvb + r0)) << 11) + kcol + sw0, KsD0);
    gload_lds16(qkb + (((size_t)(kvb + r1)) << 11) + kcol + sw1, KsD1);
    gload_lds16(vtb + ((size_t)r0 << 11) + kvb + sw0, VsD0);
    gload_lds16(vtb + ((size_t)r1 << 11) + kvb + sw1, VsD1);
    __syncthreads();

    const bool actA = (kt <= qtA);

    // ---- S = (Q/8) K^T for both q-tiles, sharing K fragments ----
    f32x4 sA[4] = {}, sB[4] = {};
#pragma unroll
    for (int kf = 0; kf < 2; ++kf)
#pragma unroll
      for (int nt = 0; nt < 4; ++nt) {
        int krow = nt * 16 + l15;
        int slot = (kf * 4 + l4) ^ (krow & 7);
        bf16x8 kf8 = __builtin_bit_cast(bf16x8,
            *(const u32x4*)((const char*)Ks + krow * 128 + (slot << 4)));
        sB[nt] = __builtin_amdgcn_mfma_f32_16x16x32_bf16(qfB[kf], kf8, sB[nt], 0, 0, 0);
        if (actA)
          sA[nt] = __builtin_amdgcn_mfma_f32_16x16x32_bf16(qfA[kf], kf8, sA[nt], 0, 0, 0);
      }

    // ---- causal masks (diagonal tiles only) ----
    if (kt == qtB) {
#pragma unroll
      for (int nt = 0; nt < 4; ++nt) {
        int col = kvb + nt * 16 + l15;
        int rowg = qtB * 64 + wid * 16 + l4 * 4;
#pragma unroll
        for (int r = 0; r < 4; ++r)
          if (col > rowg + r) sB[nt][r] = -__builtin_inff();
      }
    }
    if (actA && kt == qtA) {
#pragma unroll
      for (int nt = 0; nt < 4; ++nt) {
        int col = kvb + nt * 16 + l15;
        int rowg = qtA * 64 + wid * 16 + l4 * 4;
#pragma unroll
        for (int r = 0; r < 4; ++r)
          if (col > rowg + r) sA[nt][r] = -__builtin_inff();
      }
    }

    // ---- online softmax + P->LDS (wave-private) ----
    smx(sB, mB, lB, oB, &Ps[wid][0]);
    if (actA) smx(sA, mA, lA, oA, &Ps[4 + wid][0]);

    // ---- O += P V, sharing V fragments between the two q-tiles ----
#pragma unroll
    for (int kf = 0; kf < 2; ++kf) {
      bf16x8 pB = __builtin_bit_cast(bf16x8,
          *(const u32x4*)&Ps[wid][l15 * 72 + kf * 32 + l4 * 8]);
      bf16x8 pA;
      if (actA)
        pA = __builtin_bit_cast(bf16x8,
            *(const u32x4*)&Ps[4 + wid][l15 * 72 + kf * 32 + l4 * 8]);
#pragma unroll
      for (int dt = 0; dt < 4; ++dt) {
        int d = dt * 16 + l15;
        int slot = (kf * 4 + l4) ^ (d & 7);
        bf16x8 vf = __builtin_bit_cast(bf16x8,
            *(const u32x4*)((const char*)Vs + d * 128 + (slot << 4)));
        oB[dt] = __builtin_amdgcn_mfma_f32_16x16x32_bf16(pB, vf, oB[dt], 0, 0, 0);
        if (actA)
          oA[dt] = __builtin_amdgcn_mfma_f32_16x16x32_bf16(pA, vf, oA[dt], 0, 0, 0);
      }
    }
    __syncthreads();   // protect Ks/Vs before next tile's staging
  }

  // ---- epilogue ----
  auto epi = [&](float* l_, f32x4* o_, int qt) {
#pragma unroll
    for (int dt = 0; dt < 4; ++dt)
#pragma unroll
      for (int r = 0; r < 4; ++r) {
        float val = o_[dt][r] / l_[r];
        int tok = qt * 64 + wid * 16 + l4 * 4 + r;
        O[(((size_t)(b * S_LEN + tok)) << 10) + h * 64 + dt * 16 + l15] = f2bf(val);
      }
  };
  epi(lB, oB, qtB);
  epi(lA, oA, qtA);
}

// ---------------------------------------------------------------------------
extern "C" void kernel_launch(void* const* d_in, const int* in_sizes, int n_in,
                              void* d_out, int out_size, void* d_ws, size_t ws_size,
                              hipStream_t stream) {
  const float* x    = (const float*)d_in[0];
  const float* Wqkv = (const float*)d_in[1];
  const float* bqkv = (const float*)d_in[2];
  const float* Wout = (const float*)d_in[3];
  const float* bout = (const float*)d_in[4];
  float* out = (float*)d_out;

  // workspace layout (u16 elems): 48 MiB total
  u16* xb    = (u16*)d_ws;            // 4,194,304
  u16* wqkvb = xb + 4194304;          // 3,145,728
  u16* woutb = wqkvb + 3145728;       // 1,048,576
  u16* qkb   = woutb + 1048576;       // 8,388,608  (Q|K, [4096][2048])
  u16* vtb   = qkb + 8388608;         // 4,194,304  (V^T, [32][64][2048])
  u16* ob    = vtb + 4194304;         // 4,194,304

  f2bf_vec<<<1024, 256, 0, stream>>>(x,    xb,    4194304 / 4);
  f2bf_vec<<<1024, 256, 0, stream>>>(Wqkv, wqkvb, 3145728 / 4);
  f2bf_vec<<<512,  256, 0, stream>>>(Wout, woutb, 1048576 / 4);

  gemm_bt<2><<<dim3(24, 32), 256, 0, stream>>>(xb, wqkvb, bqkv, qkb, vtb,
                                               4096, 3072, 1024, 0);
  attn2<<<dim3(16, 32), 256, 0, stream>>>(qkb, vtb, ob);
  gemm_bt<0><<<dim3(8, 32), 256, 0, stream>>>(ob, woutb, bout, out, nullptr,
                                              4096, 1024, 1024, 1024);
}

// Round 4
// 161.793 us; speedup vs baseline: 1.3902x; 1.0006x over previous
//
#include <hip/hip_runtime.h>
#include <hip/hip_bf16.h>
#include <stdint.h>

typedef unsigned short u16;
typedef unsigned int u32;
typedef __attribute__((ext_vector_type(8))) __bf16 bf16x8;
typedef __attribute__((ext_vector_type(8))) u16 u16x8;
typedef __attribute__((ext_vector_type(4))) u16 u16x4;
typedef __attribute__((ext_vector_type(4))) float f32x4;
typedef __attribute__((ext_vector_type(4))) u32 u32x4;

#define S_LEN 2048
#define QSCALE 0.180336880f   /* (1/8) * log2(e) */

__device__ __forceinline__ u16 f2bf(float f) {
  u32 u = __builtin_bit_cast(u32, f);
  u32 r = u + 0x7fffu + ((u >> 16) & 1u);   // round-to-nearest-even
  return (u16)(r >> 16);
}
__device__ __forceinline__ float bf2f(u16 h) {
  u32 u = ((u32)h) << 16;
  return __builtin_bit_cast(float, u);
}
__device__ __forceinline__ float ex2(float x) { return __builtin_exp2f(x); }

__device__ __forceinline__ void gload_lds16(const void* g, void* l) {
  __builtin_amdgcn_global_load_lds(
      (const __attribute__((address_space(1))) void*)g,
      (__attribute__((address_space(3))) void*)l, 16, 0, 0);
}

// ---------------------------------------------------------------------------
// fp32 -> bf16 conversion (vectorized, grid-stride)
// ---------------------------------------------------------------------------
__global__ void f2bf_vec(const float* __restrict__ in, u16* __restrict__ out, int n4) {
  int i = blockIdx.x * blockDim.x + threadIdx.x;
  int stride = gridDim.x * blockDim.x;
  for (; i < n4; i += stride) {
    float4 v = ((const float4*)in)[i];
    ushort4 o;
    o.x = f2bf(v.x); o.y = f2bf(v.y); o.z = f2bf(v.z); o.w = f2bf(v.w);
    ((ushort4*)out)[i] = o;
  }
}

// ---------------------------------------------------------------------------
// C = A * B^T + bias.  A:[M,K] bf16, B:[N,K] bf16 (row-major, K contig).
// 128x128 tile, BK=32, 4 waves (2x2). MODE 0: fp32 C0 (ldc).
// MODE 2: QKV split — cols<1024 (Q) -> bf16 C0, scaled by QSCALE;
//         cols in [1024,2048) (K) -> bf16 C0 (ld 2048); cols>=2048 (V) ->
//         transposed bf16 C1 as vt[b*16+h][d][s] (packed 4-row stores).
// ---------------------------------------------------------------------------
template<int MODE>
__global__ __launch_bounds__(256) void gemm_bt(
    const u16* __restrict__ A, const u16* __restrict__ B,
    const float* __restrict__ bias, void* __restrict__ C0,
    u16* __restrict__ C1, int M, int N, int K, int ldc) {
  __shared__ __align__(16) u16 As[128 * 32];
  __shared__ __align__(16) u16 Bs[128 * 32];
  const int tid = threadIdx.x;
  const int wid = tid >> 6, lane = tid & 63;
  const int l15 = lane & 15, l4 = lane >> 4;
  const int wr = wid >> 1, wc = wid & 1;
  const int bm = blockIdx.y * 128, bn = blockIdx.x * 128;

  f32x4 acc[4][4] = {};

  for (int k0 = 0; k0 < K; k0 += 32) {
#pragma unroll
    for (int i = 0; i < 2; ++i) {
      int c = i * 256 + wid * 64 + lane;              // chunk id (16B each)
      int row = c >> 2, kc = c & 3;
      gload_lds16(A + (size_t)(bm + row) * K + k0 + kc * 8,
                  (char*)As + (i * 256 + wid * 64) * 16);
      gload_lds16(B + (size_t)(bn + row) * K + k0 + kc * 8,
                  (char*)Bs + (i * 256 + wid * 64) * 16);
    }
    __syncthreads();

    bf16x8 a[4], b[4];
#pragma unroll
    for (int mi = 0; mi < 4; ++mi)
      a[mi] = __builtin_bit_cast(bf16x8,
          *(const u32x4*)&As[(wr * 64 + mi * 16 + l15) * 32 + l4 * 8]);
#pragma unroll
    for (int ni = 0; ni < 4; ++ni)
      b[ni] = __builtin_bit_cast(bf16x8,
          *(const u32x4*)&Bs[(wc * 64 + ni * 16 + l15) * 32 + l4 * 8]);
#pragma unroll
    for (int mi = 0; mi < 4; ++mi)
#pragma unroll
      for (int ni = 0; ni < 4; ++ni)
        acc[mi][ni] = __builtin_amdgcn_mfma_f32_16x16x32_bf16(
            a[mi], b[ni], acc[mi][ni], 0, 0, 0);
    __syncthreads();
  }

#pragma unroll
  for (int ni = 0; ni < 4; ++ni) {
    int col = bn + wc * 64 + ni * 16 + l15;
    float bv = bias[col];
#pragma unroll
    for (int mi = 0; mi < 4; ++mi) {
      int row = bm + wr * 64 + mi * 16 + l4 * 4;
      if (MODE == 0) {
#pragma unroll
        for (int r = 0; r < 4; ++r)
          ((float*)C0)[(size_t)(row + r) * ldc + col] = acc[mi][ni][r] + bv;
      } else {
        if (col < 2048) {
          float sc = (col < 1024) ? QSCALE : 1.0f;
#pragma unroll
          for (int r = 0; r < 4; ++r)
            ((u16*)C0)[(size_t)(row + r) * 2048 + col] = f2bf((acc[mi][ni][r] + bv) * sc);
        } else {
          u16x4 vv;
#pragma unroll
          for (int r = 0; r < 4; ++r) vv[r] = f2bf(acc[mi][ni][r] + bv);
          int hh = (col - 2048) >> 6, d = (col - 2048) & 63;
          int bb = row >> 11, s = row & 2047;
          *(u16x4*)&C1[(((size_t)(bb * 16 + hh) * 64 + d) << 11) + s] = vv;
        }
      }
    }
  }
}

// ---------------------------------------------------------------------------
// Causal flash attention, causally balanced: block p handles q-tiles p and
// 31-p for one (b,h); both consume the same staged K/V tiles (double-buffered,
// one barrier per tile). Scores arrive in log2-domain (Q pre-scaled by
// 0.125*log2e in the GEMM epilogue). Full per-tile max reduce (round-2-proven
// logic); l kept as per-lane partials, reduced once in the epilogue.
// ---------------------------------------------------------------------------
__global__ __launch_bounds__(256, 2) void attn2(
    const u16* __restrict__ qk, const u16* __restrict__ vt, u16* __restrict__ O) {
  __shared__ __align__(16) u16 Ks[2][64 * 64];
  __shared__ __align__(16) u16 Vs[2][64 * 64];
  __shared__ __align__(16) u16 Ps[8][16 * 72];
  const int tid = threadIdx.x;
  const int wid = tid >> 6, lane = tid & 63;
  const int l15 = lane & 15, l4 = lane >> 4;
  const int p = blockIdx.x, bh = blockIdx.y;
  const int b = bh >> 4, h = bh & 15;
  const int qtA = p, qtB = 31 - p;
  const u16* qkb = qk + (((size_t)b * S_LEN) << 11);
  const u16* vtb = vt + ((size_t)bh << 17);           // 64*2048 per (b,h)
  const int qcol = h * 64, kcol = 1024 + h * 64;

  // staging chunk descriptors: chunk c -> row r = c>>3, swizzled col
  const int c0 = tid, c1 = 256 + tid;
  const int r0 = c0 >> 3, sw0 = ((c0 & 7) ^ (r0 & 7)) << 3;
  const int r1 = c1 >> 3, sw1 = ((c1 & 7) ^ (r1 & 7)) << 3;

  auto stage = [&](int buf, int kt) {
    int kvb = kt << 6;
    gload_lds16(qkb + (((size_t)(kvb + r0)) << 11) + kcol + sw0, (char*)&Ks[buf][0] + c0 * 16);
    gload_lds16(qkb + (((size_t)(kvb + r1)) << 11) + kcol + sw1, (char*)&Ks[buf][0] + c1 * 16);
    gload_lds16(vtb + ((size_t)r0 << 11) + kvb + sw0, (char*)&Vs[buf][0] + c0 * 16);
    gload_lds16(vtb + ((size_t)r1 << 11) + kvb + sw1, (char*)&Vs[buf][0] + c1 * 16);
  };

  // Q fragments (A-layout: row=l15, k=l4*8+j) — already scaled to log2 domain
  bf16x8 qfA[2], qfB[2];
  {
    int rA = qtA * 64 + wid * 16 + l15;
    int rB = qtB * 64 + wid * 16 + l15;
#pragma unroll
    for (int kf = 0; kf < 2; ++kf) {
      qfA[kf] = __builtin_bit_cast(bf16x8,
          *(const u16x8*)&qkb[((size_t)rA << 11) + qcol + kf * 32 + l4 * 8]);
      qfB[kf] = __builtin_bit_cast(bf16x8,
          *(const u16x8*)&qkb[((size_t)rB << 11) + qcol + kf * 32 + l4 * 8]);
    }
  }

  float mA[4], lA[4], mB[4], lB[4];
  f32x4 oA[4] = {}, oB[4] = {};
#pragma unroll
  for (int r = 0; r < 4; ++r) {
    mA[r] = -__builtin_inff(); lA[r] = 0.f;
    mB[r] = -__builtin_inff(); lB[r] = 0.f;
  }

  // online softmax (log2 domain, full per-tile reduce) + P write (wave-private)
  auto smx = [&](f32x4* s, float* m_, float* l_, f32x4* o_, u16* myP) {
    float pm[4], es[4];
#pragma unroll
    for (int r = 0; r < 4; ++r)
      pm[r] = fmaxf(fmaxf(s[0][r], s[1][r]), fmaxf(s[2][r], s[3][r]));
#pragma unroll
    for (int r = 0; r < 4; ++r) {
#pragma unroll
      for (int off = 1; off < 16; off <<= 1)
        pm[r] = fmaxf(pm[r], __shfl_xor(pm[r], off));
      float nm = fmaxf(m_[r], pm[r]);
      es[r] = ex2(m_[r] - nm);
      m_[r] = nm;
    }
#pragma unroll
    for (int nt = 0; nt < 4; ++nt)
#pragma unroll
      for (int r = 0; r < 4; ++r)
        s[nt][r] = ex2(s[nt][r] - m_[r]);
#pragma unroll
    for (int r = 0; r < 4; ++r)
      l_[r] = l_[r] * es[r] + ((s[0][r] + s[1][r]) + (s[2][r] + s[3][r]));
#pragma unroll
    for (int dt = 0; dt < 4; ++dt)
#pragma unroll
      for (int r = 0; r < 4; ++r) o_[dt][r] *= es[r];
#pragma unroll
    for (int nt = 0; nt < 4; ++nt)
#pragma unroll
      for (int r = 0; r < 4; ++r)
        myP[(l4 * 4 + r) * 72 + nt * 16 + l15] = f2bf(s[nt][r]);
  };

  stage(0, 0);
  for (int kt = 0; kt <= qtB; ++kt) {
    const int kvb = kt << 6;
    const int cur = kt & 1;
    __syncthreads();                       // drains stage(cur); guards buf reuse
    if (kt < qtB) stage(cur ^ 1, kt + 1);  // prefetch next tile (overlaps compute)

    const bool actA = (kt <= qtA);
    const char* Kc = (const char*)&Ks[cur][0];
    const char* Vc = (const char*)&Vs[cur][0];

    // ---- S = Q K^T (log2 domain) for both q-tiles, sharing K fragments ----
    f32x4 sA[4] = {}, sB[4] = {};
#pragma unroll
    for (int kf = 0; kf < 2; ++kf)
#pragma unroll
      for (int nt = 0; nt < 4; ++nt) {
        int krow = nt * 16 + l15;
        int slot = (kf * 4 + l4) ^ (krow & 7);
        bf16x8 kf8 = __builtin_bit_cast(bf16x8,
            *(const u32x4*)(Kc + krow * 128 + (slot << 4)));
        sB[nt] = __builtin_amdgcn_mfma_f32_16x16x32_bf16(qfB[kf], kf8, sB[nt], 0, 0, 0);
        if (actA)
          sA[nt] = __builtin_amdgcn_mfma_f32_16x16x32_bf16(qfA[kf], kf8, sA[nt], 0, 0, 0);
      }

    // ---- causal masks (diagonal tiles only) ----
    if (kt == qtB) {
#pragma unroll
      for (int nt = 0; nt < 4; ++nt) {
        int col = kvb + nt * 16 + l15;
        int rowg = qtB * 64 + wid * 16 + l4 * 4;
#pragma unroll
        for (int r = 0; r < 4; ++r)
          if (col > rowg + r) sB[nt][r] = -__builtin_inff();
      }
    }
    if (actA && kt == qtA) {
#pragma unroll
      for (int nt = 0; nt < 4; ++nt) {
        int col = kvb + nt * 16 + l15;
        int rowg = qtA * 64 + wid * 16 + l4 * 4;
#pragma unroll
        for (int r = 0; r < 4; ++r)
          if (col > rowg + r) sA[nt][r] = -__builtin_inff();
      }
    }

    // ---- online softmax + P->LDS (wave-private) ----
    smx(sB, mB, lB, oB, &Ps[wid][0]);
    if (actA) smx(sA, mA, lA, oA, &Ps[4 + wid][0]);

    // ---- O += P V, sharing V fragments between the two q-tiles ----
#pragma unroll
    for (int kf = 0; kf < 2; ++kf) {
      bf16x8 pB = __builtin_bit_cast(bf16x8,
          *(const u32x4*)&Ps[wid][l15 * 72 + kf * 32 + l4 * 8]);
      bf16x8 pA;
      if (actA)
        pA = __builtin_bit_cast(bf16x8,
            *(const u32x4*)&Ps[4 + wid][l15 * 72 + kf * 32 + l4 * 8]);
#pragma unroll
      for (int dt = 0; dt < 4; ++dt) {
        int d = dt * 16 + l15;
        int slot = (kf * 4 + l4) ^ (d & 7);
        bf16x8 vf = __builtin_bit_cast(bf16x8,
            *(const u32x4*)(Vc + d * 128 + (slot << 4)));
        oB[dt] = __builtin_amdgcn_mfma_f32_16x16x32_bf16(pB, vf, oB[dt], 0, 0, 0);
        if (actA)
          oA[dt] = __builtin_amdgcn_mfma_f32_16x16x32_bf16(pA, vf, oA[dt], 0, 0, 0);
      }
    }
  }

  // ---- epilogue: reduce l across the 16-lane row groups, normalize, store --
  auto epi = [&](float* l_, f32x4* o_, int qt) {
#pragma unroll
    for (int r = 0; r < 4; ++r) {
      float l = l_[r];
#pragma unroll
      for (int off = 1; off < 16; off <<= 1) l += __shfl_xor(l, off);
      l_[r] = 1.0f / l;
    }
#pragma unroll
    for (int dt = 0; dt < 4; ++dt)
#pragma unroll
      for (int r = 0; r < 4; ++r) {
        float val = o_[dt][r] * l_[r];
        int tok = qt * 64 + wid * 16 + l4 * 4 + r;
        O[(((size_t)(b * S_LEN + tok)) << 10) + h * 64 + dt * 16 + l15] = f2bf(val);
      }
  };
  epi(lB, oB, qtB);
  epi(lA, oA, qtA);
}

// ---------------------------------------------------------------------------
extern "C" void kernel_launch(void* const* d_in, const int* in_sizes, int n_in,
                              void* d_out, int out_size, void* d_ws, size_t ws_size,
                              hipStream_t stream) {
  const float* x    = (const float*)d_in[0];
  const float* Wqkv = (const float*)d_in[1];
  const float* bqkv = (const float*)d_in[2];
  const float* Wout = (const float*)d_in[3];
  const float* bout = (const float*)d_in[4];
  float* out = (float*)d_out;

  // workspace layout (u16 elems): 48 MiB total
  u16* xb    = (u16*)d_ws;            // 4,194,304
  u16* wqkvb = xb + 4194304;          // 3,145,728
  u16* woutb = wqkvb + 3145728;       // 1,048,576
  u16* qkb   = woutb + 1048576;       // 8,388,608  (Q|K, [4096][2048])
  u16* vtb   = qkb + 8388608;         // 4,194,304  (V^T, [32][64][2048])
  u16* ob    = vtb + 4194304;         // 4,194,304

  f2bf_vec<<<1024, 256, 0, stream>>>(x,    xb,    4194304 / 4);
  f2bf_vec<<<1024, 256, 0, stream>>>(Wqkv, wqkvb, 3145728 / 4);
  f2bf_vec<<<512,  256, 0, stream>>>(Wout, woutb, 1048576 / 4);

  gemm_bt<2><<<dim3(24, 32), 256, 0, stream>>>(xb, wqkvb, bqkv, qkb, vtb,
                                               4096, 3072, 1024, 0);
  attn2<<<dim3(16, 32), 256, 0, stream>>>(qkb, vtb, ob);
  gemm_bt<0><<<dim3(8, 32), 256, 0, stream>>>(ob, woutb, bout, out, nullptr,
                                              4096, 1024, 1024, 1024);
}